// Round 1
// baseline (175.548 us; speedup 1.0000x reference)
//
#include <hip/hip_runtime.h>
#include <hip/hip_bf16.h>
#include <stdint.h>

#define BATCH   16384
#define NCLASS  1000
#define CPAD    1024
#define FDIM    1024
#define MARGINF 5.0f

typedef __attribute__((ext_vector_type(4))) float f32x4;
typedef __attribute__((ext_vector_type(8))) short bf16x8;

__device__ __forceinline__ void gload16(const void* g, void* l) {
    __builtin_amdgcn_global_load_lds(
        (const __attribute__((address_space(1))) void*)g,
        (__attribute__((address_space(3))) void*)l, 16, 0, 0);
}

__device__ __forceinline__ unsigned short f2bf(float f) {
    __hip_bfloat16 h = __float2bfloat16(f);
    return __builtin_bit_cast(unsigned short, h);
}

// ---- prep: x fp32 -> bf16 ----
__global__ void prep_x(const float* __restrict__ x, unsigned short* __restrict__ xb, int n4) {
    int i = blockIdx.x * blockDim.x + threadIdx.x;
    int stride = gridDim.x * blockDim.x;
    for (; i < n4; i += stride) {
        float4 v = ((const float4*)x)[i];
        ushort4 o;
        o.x = f2bf(v.x); o.y = f2bf(v.y); o.z = f2bf(v.z); o.w = f2bf(v.w);
        ((ushort4*)xb)[i] = o;
    }
}

// ---- prep: centers fp32 -> bf16, c2 = sum(c*c), pad rows zeroed / c2 pad = 1e30 ----
__global__ void prep_c(const float* __restrict__ c, unsigned short* __restrict__ cb,
                       float* __restrict__ c2) {
    int k = blockIdx.x;       // 0..1023
    int t = threadIdx.x;      // 256 threads, each one float4 of the 1024-dim row
    if (k >= NCLASS) {
        ((ushort4*)(cb + (size_t)k * FDIM))[t] = make_ushort4(0, 0, 0, 0);
        if (t == 0) c2[k] = 1e30f;
        return;
    }
    float4 v = ((const float4*)(c + (size_t)k * FDIM))[t];
    ushort4 o;
    o.x = f2bf(v.x); o.y = f2bf(v.y); o.z = f2bf(v.z); o.w = f2bf(v.w);
    ((ushort4*)(cb + (size_t)k * FDIM))[t] = o;
    float ss = v.x * v.x + v.y * v.y + v.z * v.z + v.w * v.w;
    #pragma unroll
    for (int s = 1; s < 64; s <<= 1) ss += __shfl_xor(ss, s, 64);
    __shared__ float sred[4];
    int lane = t & 63, wid = t >> 6;
    if (lane == 0) sred[wid] = ss;
    __syncthreads();
    if (t == 0) c2[k] = sred[0] + sred[1] + sred[2] + sred[3];
}

// ---- fused GEMM + per-row partial min ----
// Computes t[r,c] = 0.5*c2[c] - dot(A_r, B_c) over a 128x128 tile, full K=1024.
// Per row: partial min over the tile's 128 cols (excluding col==label / col==row),
// and (main kernel only) pos[r] = t[r, label[r]] when the label col is in-tile.
template <bool EXROW>
__launch_bounds__(256)
__global__ void gemm_min(const unsigned short* __restrict__ A,   // [*][1024] bf16
                         const unsigned short* __restrict__ B,   // [1024][1024] bf16 (centers)
                         const float* __restrict__ c2,
                         const int* __restrict__ labels,
                         float* __restrict__ pmin,               // [rows][8]
                         float* __restrict__ pos)                // [rows] (main only)
{
    constexpr int BM = 128, BK = 64, KTOT = 1024, NCT = 8;
    __shared__ __align__(16) char sA[BM * BK * 2];   // 16 KB
    __shared__ __align__(16) char sB[BM * BK * 2];   // 16 KB
    __shared__ int   sLab[BM];
    __shared__ float sPM[2 * BM];

    const int t    = threadIdx.x;
    const int lane = t & 63;
    const int wave = t >> 6;
    const int wrow = wave >> 1, wcol = wave & 1;
    const int lo4  = lane & 15, hi2 = lane >> 4;

    const int rowBase = blockIdx.x * BM;
    const int colBase = blockIdx.y * BM;

    if (!EXROW) { if (t < BM) sLab[t] = labels[rowBase + t]; }

    f32x4 acc[4][4];
    #pragma unroll
    for (int m = 0; m < 4; m++)
        #pragma unroll
        for (int n = 0; n < 4; n++) acc[m][n] = (f32x4){0.f, 0.f, 0.f, 0.f};

    const int g_t = t & 7;           // granule within row
    const int r_t = t >> 3;          // row within 32-row chunk

    for (int kt = 0; kt < KTOT / BK; ++kt) {
        __syncthreads();
        const int k0 = kt * BK;
        #pragma unroll
        for (int cc = 0; cc < 4; ++cc) {
            const int row = cc * 32 + r_t;
            const int sc  = g_t ^ (row & 7);     // inverse-swizzled global granule
            const unsigned short* ga = A + (size_t)(rowBase + row) * KTOT + k0 + sc * 8;
            const unsigned short* gb = B + (size_t)(colBase + row) * KTOT + k0 + sc * 8;
            // wave-uniform LDS base; HW adds lane*16
            char* la = sA + (cc * 256 + (t & 192)) * 16;
            char* lb = sB + (cc * 256 + (t & 192)) * 16;
            gload16(ga, la);
            gload16(gb, lb);
        }
        __syncthreads();
        #pragma unroll
        for (int ks = 0; ks < 2; ++ks) {
            bf16x8 af[4], bfr[4];
            #pragma unroll
            for (int m = 0; m < 4; m++) {
                const int r    = wrow * 64 + m * 16 + lo4;
                const int slot = (ks * 4 + hi2) ^ (r & 7);
                af[m] = *(const bf16x8*)(sA + r * 128 + slot * 16);
            }
            #pragma unroll
            for (int n = 0; n < 4; n++) {
                const int r    = wcol * 64 + n * 16 + lo4;
                const int slot = (ks * 4 + hi2) ^ (r & 7);
                bfr[n] = *(const bf16x8*)(sB + r * 128 + slot * 16);
            }
            #pragma unroll
            for (int m = 0; m < 4; m++)
                #pragma unroll
                for (int n = 0; n < 4; n++)
                    acc[m][n] = __builtin_amdgcn_mfma_f32_16x16x32_bf16(af[m], bfr[n], acc[m][n], 0, 0, 0);
        }
    }

    // ---- epilogue: bias + exclusion + per-row min ----
    float bias[4]; int colg[4];
    #pragma unroll
    for (int n = 0; n < 4; n++) {
        const int col = colBase + wcol * 64 + n * 16 + lo4;
        colg[n] = col;
        bias[n] = 0.5f * c2[col];          // c2[col>=1000] = 1e30 masks padding
    }
    #pragma unroll
    for (int m = 0; m < 4; m++) {
        #pragma unroll
        for (int j = 0; j < 4; j++) {
            const int rloc  = wrow * 64 + m * 16 + hi2 * 4 + j;
            const int rglob = rowBase + rloc;
            const int lab   = EXROW ? rglob : sLab[rloc];
            float vmin = 1e30f;
            #pragma unroll
            for (int n = 0; n < 4; n++) {
                float tv = acc[m][n][j] + bias[n];
                if (colg[n] == lab) {
                    if (!EXROW) pos[rglob] = tv;   // unique writer across grid
                    tv = 1e30f;
                }
                vmin = fminf(vmin, tv);
            }
            vmin = fminf(vmin, __shfl_xor(vmin, 1, 64));
            vmin = fminf(vmin, __shfl_xor(vmin, 2, 64));
            vmin = fminf(vmin, __shfl_xor(vmin, 4, 64));
            vmin = fminf(vmin, __shfl_xor(vmin, 8, 64));
            if (lo4 == 0) sPM[wcol * BM + rloc] = vmin;
        }
    }
    __syncthreads();
    if (t < BM) {
        const float v = fminf(sPM[t], sPM[BM + t]);
        pmin[(size_t)(rowBase + t) * NCT + blockIdx.y] = v;
    }
}

// ---- cmin[k] = 0.5*c2[k] + min over 8 tile-partials ----
__global__ void cmin_k(const float* __restrict__ c2, const float* __restrict__ cpmin,
                       float* __restrict__ cmin) {
    int k = blockIdx.x * blockDim.x + threadIdx.x;
    if (k >= NCLASS) return;
    float v = 1e30f;
    #pragma unroll
    for (int i = 0; i < 8; i++) v = fminf(v, cpmin[k * 8 + i]);
    cmin[k] = 0.5f * c2[k] + v;
}

// ---- per-row loss + block partial sums ----
__global__ void loss_k(const float* __restrict__ pmin, const float* __restrict__ pos,
                       const int* __restrict__ labels, const float* __restrict__ cmin,
                       float* __restrict__ partial) {
    int r = blockIdx.x * 256 + threadIdx.x;
    float neg = 1e30f;
    #pragma unroll
    for (int i = 0; i < 8; i++) neg = fminf(neg, pmin[(size_t)r * 8 + i]);
    float l1 = fmaxf(pos[r] + MARGINF - neg, 0.f);
    float l2 = fmaxf(MARGINF + 2.0f - cmin[labels[r]], 0.f);
    float v  = l1 + l2;
    #pragma unroll
    for (int s = 1; s < 64; s <<= 1) v += __shfl_xor(v, s, 64);
    __shared__ float sred[4];
    int lane = threadIdx.x & 63, wid = threadIdx.x >> 6;
    if (lane == 0) sred[wid] = v;
    __syncthreads();
    if (threadIdx.x == 0) partial[blockIdx.x] = sred[0] + sred[1] + sred[2] + sred[3];
}

__global__ void sum_k(const float* __restrict__ partial, float* __restrict__ out) {
    float v = partial[threadIdx.x];   // 64 threads
    #pragma unroll
    for (int s = 1; s < 64; s <<= 1) v += __shfl_xor(v, s, 64);
    if (threadIdx.x == 0) out[0] = v / (float)BATCH;
}

extern "C" void kernel_launch(void* const* d_in, const int* in_sizes, int n_in,
                              void* d_out, int out_size, void* d_ws, size_t ws_size,
                              hipStream_t stream) {
    const float* x       = (const float*)d_in[0];
    const int*   labels  = (const int*)d_in[1];
    const float* centers = (const float*)d_in[2];
    float* out = (float*)d_out;

    char* ws = (char*)d_ws;
    size_t off = 0;
    unsigned short* xb = (unsigned short*)(ws + off); off += (size_t)BATCH * FDIM * 2;  // 33.55 MB
    unsigned short* cb = (unsigned short*)(ws + off); off += (size_t)CPAD * FDIM * 2;   //  2.10 MB
    float* c2      = (float*)(ws + off); off += (size_t)CPAD * 4;
    float* pmin    = (float*)(ws + off); off += (size_t)BATCH * 8 * 4;
    float* pos     = (float*)(ws + off); off += (size_t)BATCH * 4;
    float* cpmin   = (float*)(ws + off); off += (size_t)CPAD * 8 * 4;
    float* cmin    = (float*)(ws + off); off += (size_t)CPAD * 4;
    float* partial = (float*)(ws + off); off += 64 * 4;

    prep_x<<<dim3(2048), dim3(256), 0, stream>>>(x, xb, BATCH * FDIM / 4);
    prep_c<<<dim3(CPAD), dim3(256), 0, stream>>>(centers, cb, c2);
    gemm_min<false><<<dim3(BATCH / 128, 8), dim3(256), 0, stream>>>(xb, cb, c2, labels, pmin, pos);
    gemm_min<true><<<dim3(CPAD / 128, 8), dim3(256), 0, stream>>>(cb, cb, c2, nullptr, cpmin, nullptr);
    cmin_k<<<dim3(4), dim3(256), 0, stream>>>(c2, cpmin, cmin);
    loss_k<<<dim3(BATCH / 256), dim3(256), 0, stream>>>(pmin, pos, labels, cmin, partial);
    sum_k<<<dim3(1), dim3(64), 0, stream>>>(partial, out);
}